// Round 13
// baseline (55.874 us; speedup 1.0000x reference)
//
#include <hip/hip_runtime.h>

#define IMG_H 256
#define IMG_W 256
#define ROWS 16
#define NIMG 128
#define NWAVES (NIMG * 64)   // 8192: img x 16 row-strips x 4 col-quarters

__device__ __forceinline__ float ssim1(float mu1, float mu2, float spp, float stt, float spt) {
    const float C1 = 1e-4f, C2 = 9e-4f;
    float mu1s = mu1 * mu1, mu2s = mu2 * mu2, mu12 = mu1 * mu2;
    float s1 = spp - mu1s, s2 = stt - mu2s, s12 = spt - mu12;
    float num = (2.f * mu12 + C1) * (2.f * s12 + C2);
    float den = (mu1s + mu2s + C1) * (s1 + s2 + C2);
    return num * __builtin_amdgcn_rcpf(den);
}

// H-first separable SSIM, LDS-row family, DOUBLE-DECOUPLED pipeline (R13).
// R12 post-mortem: occupancy fixes never moved VALU past ~44% because each
// step kept a serial ds_write->ds_read->lgkm->compute chain (~120+cyc) and
// identical waves stall in phase. Now BOTH latencies span a full step:
//   - global loads: row j+2 issued at step j (R11-proven)
//   - LDS reads:   row j+1's 7x ds_read_b64 issued at step j into the
//     NEXT-gen q regs; step j computes from CURRENT-gen q regs whose reads
//     were issued at step j-1 (lgkm wait ~free at use)
// Single LDS buffer (same-wave DS is in-order: write j+1 then read j+1 is
// race-free; HW-proven R8-R12). Window is mod-8 (40 regs) so the steady
// loop is 2x8 steps and qA/qB parity is static per body position -> the
// VGPR-proven rolled-loop shape survives. 1 col/thread, 4 waves/block,
// private LDS quadrants, no barriers.
template<int ATOMIC>
__global__ __launch_bounds__(256) void ssim_main(
    const float* __restrict__ pred,
    const float* __restrict__ targ,
    const float* __restrict__ window,
    float* __restrict__ wsum)
{
    __shared__ float2 sbuf[4][72];    // [wave][col c at idx c-X0+4]

    const int lane = threadIdx.x & 63;
    const int wid  = threadIdx.x >> 6;
    const int gw   = blockIdx.x * 4 + wid;   // 0..8191
    const int n    = gw >> 6;                // image
    const int r    = gw & 63;
    const int r0   = (r >> 2) * ROWS;        // strip start row
    const int X0   = (r & 3) << 6;           // col quarter: 0/64/128/192

    // exact 1D gaussian from w2d row 3: g[j] = w[21+j] / sum
    float g[7];
    {
        float sum = 0.f;
#pragma unroll
        for (int j = 0; j < 7; ++j) { g[j] = window[21 + j]; sum += g[j]; }
        float inv = 1.f / sum;
#pragma unroll
        for (int j = 0; j < 7; ++j) g[j] *= inv;
    }

    const float* pimg = pred + (size_t)n * (IMG_H * IMG_W);
    const float* timg = targ + (size_t)n * (IMG_H * IMG_W);
    const int mo = X0 + lane;         // own column

    // halo duty, lanes 0..5: left cols X0-3..X0-1 (idx 1..3),
    // right cols X0+64..X0+66 (idx 68..70)
    int hidx = 0, hcol = 0;
    if (lane < 3)      { hidx = lane + 1;  hcol = X0 - 3 + lane;  }
    else if (lane < 6) { hidx = lane + 65; hcol = X0 + 61 + lane; }
    const bool hv = (lane < 6) && ((unsigned)hcol < (unsigned)IMG_W);

    // mod-8 register window: 5 quantities x 8 slots (all static indices)
    float Amu[8], Atu[8], App[8], Att[8], Apt[8];
    // two q generations (7-col neighborhoods), static indices only
    float2 qA[7], qB[7];
    float acc = 0.f;

    float Pr, Tr;        // global prefetch regs (own column)
    float2 Hr;           // global prefetch reg (halo col)

    float2* sw       = sbuf[wid];
    const float2* sb = sbuf[wid];

#define GLOAD(J) { \
    const int j_ = (J); \
    Pr = 0.f; Tr = 0.f; Hr = make_float2(0.f, 0.f); \
    if ((unsigned)j_ < (unsigned)IMG_H) { \
        Pr = pimg[j_ * IMG_W + mo]; \
        Tr = timg[j_ * IMG_W + mo]; \
        if (hv) { \
            Hr.x = pimg[j_ * IMG_W + hcol]; \
            Hr.y = timg[j_ * IMG_W + hcol]; \
        } \
    } }

#define TAP(K, Q) { \
    float p = (Q).x, t = (Q).y; \
    float wp = g[K] * p, wt = g[K] * t; \
    m_  = fmaf(g[K], p, m_);  u_  = fmaf(g[K], t, u_); \
    pp_ = fmaf(wp, p, pp_);   tt_ = fmaf(wt, t, tt_); \
    pt_ = fmaf(wp, t, pt_); }

#define VD8(A_, VB) ( fmaf(g[6], A_[((VB)+6)&7], fmaf(g[5], A_[((VB)+5)&7], \
    fmaf(g[4], A_[((VB)+4)&7], fmaf(g[3], A_[((VB)+3)&7], fmaf(g[2], A_[((VB)+2)&7], \
    fmaf(g[1], A_[((VB)+1)&7], g[0] * A_[(VB)&7])))))) )

#define OUTR(VB) { \
    float m1 = VD8(Amu,VB), m2 = VD8(Atu,VB), pp = VD8(App,VB), \
          tt = VD8(Att,VB), pt = VD8(Apt,VB); \
    acc += ssim1(m1, m2, pp, tt, pt); }

// step jj (row j = r0-3+jj). Entry invariant:
//   QC = row j's 7-col LDS neighborhood (reads issued at step jj-1)
//   Pr/Tr/Hr = row j+1's global data   (loaded at step jj-1)
// Body: stage row j+1; issue reads row j+1 -> QN; prefetch row j+2;
// H-conv row j from QC into slot; optional output row.
#define STEPX(SLOT, QC, QN, JNEXT, HASOUT, VB, DOLOAD) { \
    sw[lane + 4] = make_float2(Pr, Tr); \
    if (lane < 6) sw[hidx] = Hr; \
    QN[0] = sb[lane + 1]; QN[1] = sb[lane + 2]; QN[2] = sb[lane + 3]; \
    QN[3] = sb[lane + 4]; QN[4] = sb[lane + 5]; QN[5] = sb[lane + 6]; \
    QN[6] = sb[lane + 7]; \
    if (DOLOAD) { GLOAD(JNEXT); } \
    { \
        float m_ = 0.f, u_ = 0.f, pp_ = 0.f, tt_ = 0.f, pt_ = 0.f; \
        TAP(0, QC[0]) TAP(1, QC[1]) TAP(2, QC[2]) TAP(3, QC[3]) \
        TAP(4, QC[4]) TAP(5, QC[5]) TAP(6, QC[6]) \
        Amu[SLOT] = m_; Atu[SLOT] = u_; App[SLOT] = pp_; \
        Att[SLOT] = tt_; Apt[SLOT] = pt_; \
    } \
    if (HASOUT) { OUTR(VB) } }

    // prologue: establish invariant (qA = row r0-3 data; Pr = row r0-2)
    GLOAD(r0 - 3);
    sw[lane + 4] = make_float2(Pr, Tr);
    if (lane < 6) sw[hidx] = Hr;
    qA[0] = sb[lane + 1]; qA[1] = sb[lane + 2]; qA[2] = sb[lane + 3];
    qA[3] = sb[lane + 4]; qA[4] = sb[lane + 5]; qA[5] = sb[lane + 6];
    qA[6] = sb[lane + 7];
    GLOAD(r0 - 2);

    // steps 0..5: rows r0-3..r0+2 -> slots 0..5, no output
    STEPX(0, qA, qB, r0 - 1, 0, 0, 1)
    STEPX(1, qB, qA, r0,     0, 0, 1)
    STEPX(2, qA, qB, r0 + 1, 0, 0, 1)
    STEPX(3, qB, qA, r0 + 2, 0, 0, 1)
    STEPX(4, qA, qB, r0 + 3, 0, 0, 1)
    STEPX(5, qB, qA, r0 + 4, 0, 0, 1)

    // steady: 2 x 8 steps = rows r0+3..r0+18, outputs r0..r0+15.
    // Slots 6,7,0..5 and qA/qB parity are static per body position; rows
    // past r0+18 prefetch OOB-guarded zeros (harmless, keeps body uniform).
#pragma unroll 1
    for (int jb = 0; jb < 2; ++jb) {
        const int jbase = r0 + 5 + jb * 8;   // JNEXT at body position 0
        STEPX(6, qA, qB, jbase,     1, 0, 1)
        STEPX(7, qB, qA, jbase + 1, 1, 1, 1)
        STEPX(0, qA, qB, jbase + 2, 1, 2, 1)
        STEPX(1, qB, qA, jbase + 3, 1, 3, 1)
        STEPX(2, qA, qB, jbase + 4, 1, 4, 1)
        STEPX(3, qB, qA, jbase + 5, 1, 5, 1)
        STEPX(4, qA, qB, jbase + 6, 1, 6, 1)
        STEPX(5, qB, qA, jbase + 7, 1, 7, 1)
    }

#undef GLOAD
#undef TAP
#undef VD8
#undef OUTR
#undef STEPX

    // wave reduce, one write (or atomic) per wave
#pragma unroll
    for (int off = 32; off > 0; off >>= 1)
        acc += __shfl_xor(acc, off, 64);
    if (lane == 0) {
        if (ATOMIC) atomicAdd(&wsum[0], acc);
        else        wsum[gw] = acc;
    }
}

// deterministic f64 tree-reduce of the 8192 per-wave partials
__global__ __launch_bounds__(256) void ssim_final_arr(
    const float* __restrict__ ws, float* __restrict__ out)
{
    __shared__ double sred[4];
    double sm = 0.0;
#pragma unroll
    for (int k = 0; k < NWAVES / 256; ++k)
        sm += (double)ws[threadIdx.x + k * 256];
#pragma unroll
    for (int off = 32; off > 0; off >>= 1)
        sm += __shfl_down(sm, off, 64);
    const int lane = threadIdx.x & 63, wid = threadIdx.x >> 6;
    if (lane == 0) sred[wid] = sm;
    __syncthreads();
    if (threadIdx.x == 0) {
        double tot = sred[0] + sred[1] + sred[2] + sred[3];
        out[0] = (float)(1.0 - tot * (1.0 / (128.0 * 256.0 * 256.0)));
    }
}

__global__ void ssim_final_sc(const float* __restrict__ ws, float* __restrict__ out)
{
    out[0] = 1.0f - ws[0] * (1.0f / (128.0f * 256.0f * 256.0f));
}

extern "C" void kernel_launch(void* const* d_in, const int* in_sizes, int n_in,
                              void* d_out, int out_size, void* d_ws, size_t ws_size,
                              hipStream_t stream)
{
    const float* pred   = (const float*)d_in[0];
    const float* targ   = (const float*)d_in[1];
    const float* window = (const float*)d_in[2];
    float* out = (float*)d_out;
    float* ws  = (float*)d_ws;

    if (ws_size >= NWAVES * sizeof(float)) {
        // every ws slot is written by the grid each call: no memset needed
        ssim_main<0><<<NWAVES / 4, 256, 0, stream>>>(pred, targ, window, ws);
        ssim_final_arr<<<1, 256, 0, stream>>>(ws, out);
    } else {
        hipMemsetAsync(ws, 0, sizeof(float), stream);
        ssim_main<1><<<NWAVES / 4, 256, 0, stream>>>(pred, targ, window, ws);
        ssim_final_sc<<<1, 1, 0, stream>>>(ws, out);
    }
    (void)in_sizes; (void)n_in; (void)out_size;
}